// Round 1
// baseline (84.074 us; speedup 1.0000x reference)
//
#include <hip/hip_runtime.h>

// Problem constants (from reference setup_inputs)
#define NUM_TOKENS 32768
#define HIDDEN     2048
#define IVS        32000
#define SLOTS      64
#define MAX_HYPER  1024

// One block per token: resolve the source row once, then do a coalesced
// float4 row copy (2048 fp32 = 512 float4 = 2 per thread at 256 threads).
__global__ __launch_bounds__(256)
void zip2zip_embed_kernel(const int*   __restrict__ input_,
                          const int*   __restrict__ t2b,
                          const int*   __restrict__ pool_idx,
                          const float* __restrict__ weight,
                          const float* __restrict__ ebuf,
                          float*       __restrict__ out)
{
    const int token = blockIdx.x;
    const int tid   = threadIdx.x;

    const int id = input_[token];

    const float4* src = nullptr;
    if (id < IVS) {
        // base vocab row
        src = reinterpret_cast<const float4*>(weight + (size_t)id * HIDDEN);
    } else {
        const int hid = id - IVS;
        if (hid < MAX_HYPER) {
            const int slot = pool_idx[t2b[token]];
            src = reinterpret_cast<const float4*>(
                ebuf + ((size_t)slot * MAX_HYPER + (size_t)hid) * HIDDEN);
        }
        // else: out-of-range hyper id -> zeros
    }

    float4* dst = reinterpret_cast<float4*>(out + (size_t)token * HIDDEN);
    constexpr int NV = HIDDEN / 4;  // 512 float4 per row

    if (src) {
        #pragma unroll
        for (int j = tid; j < NV; j += 256) {
            dst[j] = src[j];
        }
    } else {
        const float4 z = make_float4(0.f, 0.f, 0.f, 0.f);
        #pragma unroll
        for (int j = tid; j < NV; j += 256) {
            dst[j] = z;
        }
    }
}

extern "C" void kernel_launch(void* const* d_in, const int* in_sizes, int n_in,
                              void* d_out, int out_size, void* d_ws, size_t ws_size,
                              hipStream_t stream) {
    // setup_inputs order:
    //   0: input_                     [NUM_TOKENS] int32
    //   1: token_to_batch_indices     [NUM_TOKENS] int32
    //   2: hyper_weight_pool_indices  [BATCH]      int32
    //   3: weight                     [IVS, HIDDEN]            float32
    //   4: embedding_buffer           [SLOTS, MAX_HYPER, HIDDEN] float32
    const int*   input_ = (const int*)d_in[0];
    const int*   t2b    = (const int*)d_in[1];
    const int*   pool   = (const int*)d_in[2];
    const float* weight = (const float*)d_in[3];
    const float* ebuf   = (const float*)d_in[4];
    float*       out    = (float*)d_out;

    zip2zip_embed_kernel<<<NUM_TOKENS, 256, 0, stream>>>(
        input_, t2b, pool, weight, ebuf, out);
}

// Round 2
// 82.501 us; speedup vs baseline: 1.0191x; 1.0191x over previous
//
#include <hip/hip_runtime.h>

// Problem constants (from reference setup_inputs)
#define NUM_TOKENS 32768
#define HIDDEN     2048
#define IVS        32000
#define SLOTS      64
#define MAX_HYPER  1024

typedef float f32x4 __attribute__((ext_vector_type(4)));

// One WAVE (64 lanes) per token: branch is wave-uniform; each lane moves
// 8 x float4 = 128 B. 4 tokens per 256-thread block -> 8192 blocks.
// Output stores are non-temporal (write-once) so they don't evict the
// gathered rows from L2/L3 -- duplicate token ids then re-hit cache.
__global__ __launch_bounds__(256)
void zip2zip_embed_kernel(const int*   __restrict__ input_,
                          const int*   __restrict__ t2b,
                          const int*   __restrict__ pool_idx,
                          const float* __restrict__ weight,
                          const float* __restrict__ ebuf,
                          float*       __restrict__ out)
{
    const int wave  = threadIdx.x >> 6;            // 0..3
    const int lane  = threadIdx.x & 63;
    const int token = (blockIdx.x << 2) + wave;

    const int id = input_[token];

    const f32x4* src = nullptr;
    if (id < IVS) {
        src = reinterpret_cast<const f32x4*>(weight + (size_t)id * HIDDEN);
    } else {
        const int hid = id - IVS;
        if (hid < MAX_HYPER) {   // always true for this input range; kept for safety
            const int slot = pool_idx[t2b[token]];
            src = reinterpret_cast<const f32x4*>(
                ebuf + ((size_t)slot * MAX_HYPER + (size_t)hid) * HIDDEN);
        }
    }

    f32x4* dst = reinterpret_cast<f32x4*>(out + (size_t)token * HIDDEN);
    constexpr int NV = HIDDEN / 4;  // 512 float4 per row; 8 per lane

    if (src) {
        f32x4 v[8];
        #pragma unroll
        for (int j = 0; j < 8; ++j) {
            v[j] = src[lane + j * 64];
        }
        #pragma unroll
        for (int j = 0; j < 8; ++j) {
            __builtin_nontemporal_store(v[j], &dst[lane + j * 64]);
        }
    } else {
        const f32x4 z = {0.f, 0.f, 0.f, 0.f};
        #pragma unroll
        for (int j = 0; j < 8; ++j) {
            __builtin_nontemporal_store(z, &dst[lane + j * 64]);
        }
    }
    (void)NV;
}

extern "C" void kernel_launch(void* const* d_in, const int* in_sizes, int n_in,
                              void* d_out, int out_size, void* d_ws, size_t ws_size,
                              hipStream_t stream) {
    // setup_inputs order:
    //   0: input_                     [NUM_TOKENS] int32
    //   1: token_to_batch_indices     [NUM_TOKENS] int32
    //   2: hyper_weight_pool_indices  [BATCH]      int32
    //   3: weight                     [IVS, HIDDEN]              float32
    //   4: embedding_buffer           [SLOTS, MAX_HYPER, HIDDEN] float32
    const int*   input_ = (const int*)d_in[0];
    const int*   t2b    = (const int*)d_in[1];
    const int*   pool   = (const int*)d_in[2];
    const float* weight = (const float*)d_in[3];
    const float* ebuf   = (const float*)d_in[4];
    float*       out    = (float*)d_out;

    zip2zip_embed_kernel<<<NUM_TOKENS / 4, 256, 0, stream>>>(
        input_, t2b, pool, weight, ebuf, out);
}